// Round 4
// baseline (132.590 us; speedup 1.0000x reference)
//
#include <hip/hip_runtime.h>
#include <hip/hip_bf16.h>

#define BB 64
#define TT 1024
#define NN 512
#define TCH 8
#define KT 32

static constexpr float THR = 0.15f;

typedef __attribute__((ext_vector_type(8))) short bf16x8;
typedef __attribute__((ext_vector_type(4))) float f32x4;

// ---------------- kernel A: partial column sums (s1, s2) ----------------
__global__ __launch_bounds__(512) void colsum_partial(
    const float* __restrict__ x, float* __restrict__ s1p, float* __restrict__ s2p) {
    int b = blockIdx.x;
    int c = blockIdx.y;
    int n = threadIdx.x;                 // 0..511, coalesced over n
    const float* xb = x + (size_t)b * TT * NN;
    float s1 = 0.f, s2 = 0.f;
    int t0 = c * (TT / TCH);
    #pragma unroll 4
    for (int t = t0; t < t0 + TT / TCH; ++t) {
        float v = xb[(size_t)t * NN + n];
        s1 += v;
        s2 += v * v;
    }
    s1p[((size_t)b * TCH + c) * NN + n] = s1;
    s2p[((size_t)b * TCH + c) * NN + n] = s2;
}

// ---------------- kernel A2: reduce partials -> s1, d ----------------
__global__ __launch_bounds__(512) void colsum_reduce(
    const float* __restrict__ s1p, const float* __restrict__ s2p,
    float* __restrict__ s1, float* __restrict__ dv) {
    int b = blockIdx.x;
    int n = threadIdx.x;
    float a = 0.f, q = 0.f;
    #pragma unroll
    for (int c = 0; c < TCH; ++c) {
        a += s1p[((size_t)b * TCH + c) * NN + n];
        q += s2p[((size_t)b * TCH + c) * NN + n];
    }
    s1[(size_t)b * NN + n] = a;
    dv[(size_t)b * NN + n] = q - a * a * (1.0f / TT);   // = cov_ii (unnormalized)
}

// ---------------- kernel B: split-bf16 MFMA SYRK ----------------
// Round-3 structure (128x128 tile, 640 blocks, 512 thr = 8 waves of 32x64 tiles,
// single 32 KiB LDS buffer, 2 barriers/K-step, slot-swizzled col-major LDS, RTZ
// Dekker split, register prefetch vA/vB one K-step ahead) with ONE change:
// RAW BARRIERS (T4). __syncthreads() emits s_waitcnt vmcnt(0) before s_barrier,
// draining the prefetched loads at barrier 1 -- measured round 3: prefetch gained
// only ~5% because of this. Raw __builtin_amdgcn_s_barrier + lgkmcnt(0)-only fence
// keeps the 8 prefetch loads in flight across barrier+COMPUTE; the compiler's
// dependency-counted vmcnt(8) for the consumed set lands at the next WRITE.
// LDS fencing: lgkmcnt(0) + "memory" clobber BEFORE each barrier (ds_writes visible,
// stores can't sink past), sched_barrier(0) AFTER (ds_reads can't hoist above; rule #18).
// LDS layout: Ah 0, Al 8K, Bh 16K, Bl 24K; byte(col,k) = col*64
//   + (((k>>3) ^ ((col>>1)&3))&3)*16 + (k&7)*2  -- verified conflict-free (0 conflicts).
__global__ __launch_bounds__(512, 4) void corr_mfma(
    const float* __restrict__ x, const float* __restrict__ s1,
    const float* __restrict__ dv, unsigned* __restrict__ fired) {
    __shared__ uint4 ldsbuf[2048];          // 32 KiB
    char* base = (char*)ldsbuf;

    int id = blockIdx.x;
    // XCD-chunked swizzle (640 = 8 * 80): all 10 tiles of a batch land on one XCD
    int swz = ((id & 7) * 80) + (id >> 3);
    int b = swz / 10;
    int u = swz % 10;
    int ti = 0, rem = u;
    while (rem >= (4 - ti)) { rem -= (4 - ti); ++ti; }
    int tj = ti + rem;
    int i0 = ti * 128, j0 = tj * 128;
    bool diag = (ti == tj);

    const unsigned* xb = (const unsigned*)(x + (size_t)b * TT * NN);
    int tid = threadIdx.x;
    int wave = tid >> 6;
    int lane = tid & 63;
    int rl = lane & 15, kg = lane >> 4;

    // ---- staging role: col-pair cp (0-63 A-panel, 64-127 B-panel), k-octet kq ----
    int cp = tid & 127;
    int kq = tid >> 7;                      // 0..3 -> k in [8*kq, 8*kq+8)
    int spanel = cp >> 6;                   // 0 = A (i-panel), 1 = B (j-panel)
    int pl = cp & 63;                       // pair index within panel -> cols 2pl, 2pl+1
    int gcol = (spanel ? j0 : i0) + 2 * pl;
    char* sh = base + (spanel ? 16384 : 0);
    char* sl = sh + 8192;
    unsigned sg = (unsigned)(pl & 3);       // ((col>>1)&3) for both cols of the pair
    bool do_stage = !(diag && spanel);      // diagonal tiles: stage A only

    auto LOADS = [&](uint2* v, int step) {
        const unsigned* src = xb + (size_t)(step * KT + 8 * kq) * NN + gcol;
        #pragma unroll
        for (int j = 0; j < 8; ++j)
            v[j] = *(const uint2*)(src + (size_t)j * NN);
    };
    auto WRITE = [&](const uint2* v) {
        #pragma unroll
        for (int w = 0; w < 2; ++w) {
            int p = (((cp >> 2) & 1) ^ w);      // bank-quad parity order
            unsigned coll = (unsigned)(2 * pl + p);
            unsigned h32[4], l32[4];
            #pragma unroll
            for (int q = 0; q < 4; ++q) {
                unsigned u0 = p ? v[2 * q].y     : v[2 * q].x;
                unsigned u1 = p ? v[2 * q + 1].y : v[2 * q + 1].x;
                unsigned m0 = u0 & 0xFFFF0000u, m1 = u1 & 0xFFFF0000u;
                float r0 = __uint_as_float(u0) - __uint_as_float(m0);  // exact
                float r1 = __uint_as_float(u1) - __uint_as_float(m1);  // exact
                h32[q] = (u0 >> 16) | m1;
                l32[q] = (__float_as_uint(r0) >> 16) | (__float_as_uint(r1) & 0xFFFF0000u);
            }
            unsigned off = coll * 64u + ((((unsigned)kq ^ sg) & 3u) << 4);
            *(uint4*)(sh + off) = make_uint4(h32[0], h32[1], h32[2], h32[3]);
            *(uint4*)(sl + off) = make_uint4(l32[0], l32[1], l32[2], l32[3]);
        }
    };

    // raw barrier: ds ops drained, vmcnt NOT drained (prefetch stays in flight)
    #define BAR()                                                   \
        do {                                                        \
            asm volatile("s_waitcnt lgkmcnt(0)" ::: "memory");      \
            __builtin_amdgcn_s_barrier();                           \
            __builtin_amdgcn_sched_barrier(0);                      \
        } while (0)

    // ---- compute role: wave (wr, wc) owns rows [32*wr,+32) x cols [64*wc,+64) ----
    int wr = wave >> 1, wc = wave & 1;
    const char* arh = base;
    const char* arl = base + 8192;
    const char* brh = base + (diag ? 0 : 16384);
    const char* brl = base + (diag ? 8192 : 24576);
    bool skip_mm = diag && (wc == 0) && (wr >= 2);   // fully below diagonal

    f32x4 acc[2][4];
    #pragma unroll
    for (int i = 0; i < 2; ++i)
        #pragma unroll
        for (int j = 0; j < 4; ++j)
            acc[i][j] = (f32x4)0.0f;

    unsigned aoff[2], boff[4];
    #pragma unroll
    for (int f = 0; f < 2; ++f) {
        unsigned ca = (unsigned)(32 * wr + 16 * f + rl);
        aoff[f] = ca * 64u + ((((unsigned)kg ^ ((ca >> 1) & 3u)) & 3u) << 4);
    }
    #pragma unroll
    for (int f = 0; f < 4; ++f) {
        unsigned cb = (unsigned)(64 * wc + 16 * f + rl);
        boff[f] = cb * 64u + ((((unsigned)kg ^ ((cb >> 1) & 3u)) & 3u) << 4);
    }

    #define COMPUTE()                                                                      \
        do {                                                                               \
            if (!skip_mm) {                                                                \
                bf16x8 Ah[2], Al[2];                                                       \
                _Pragma("unroll")                                                          \
                for (int f = 0; f < 2; ++f) {                                              \
                    Ah[f] = *(const bf16x8*)(arh + aoff[f]);                               \
                    Al[f] = *(const bf16x8*)(arl + aoff[f]);                               \
                }                                                                          \
                _Pragma("unroll")                                                          \
                for (int fj = 0; fj < 4; ++fj) {                                           \
                    bf16x8 Bh = *(const bf16x8*)(brh + boff[fj]);                          \
                    bf16x8 Bl = *(const bf16x8*)(brl + boff[fj]);                          \
                    _Pragma("unroll")                                                      \
                    for (int fi = 0; fi < 2; ++fi) {                                       \
                        acc[fi][fj] = __builtin_amdgcn_mfma_f32_16x16x32_bf16(             \
                            Ah[fi], Bh, acc[fi][fj], 0, 0, 0);                             \
                        acc[fi][fj] = __builtin_amdgcn_mfma_f32_16x16x32_bf16(             \
                            Ah[fi], Bl, acc[fi][fj], 0, 0, 0);                             \
                        acc[fi][fj] = __builtin_amdgcn_mfma_f32_16x16x32_bf16(             \
                            Al[fi], Bh, acc[fi][fj], 0, 0, 0);                             \
                    }                                                                      \
                }                                                                          \
            }                                                                              \
        } while (0)

    uint2 vA[8], vB[8];
    if (do_stage) LOADS(vA, 0);

    for (int it = 0; it < 32; it += 2) {
        // ---- step it: consume vA, prefetch vB (step it+1) ----
        if (do_stage) {
            LOADS(vB, it + 1);               // stays in flight across barrier+COMPUTE
            WRITE(vA);                       // compiler waits vmcnt(8) for vA only
        }
        BAR();
        COMPUTE();
        BAR();
        // ---- step it+1: consume vB, prefetch vA (step it+2) ----
        if (do_stage) {
            if (it + 2 < 32) LOADS(vA, it + 2);
            WRITE(vB);
        }
        BAR();
        COMPUTE();
        BAR();
    }
    #undef COMPUTE
    #undef BAR

    // ---- epilogue: cov = acc - s1_i*s1_j/T; fired if cov^2 > thr^2*d_i*d_j, j>i ----
    const float thr2 = THR * THR;
    const float invT = 1.0f / TT;
    const float* s1b = s1 + (size_t)b * NN;
    const float* dvb = dv + (size_t)b * NN;
    unsigned* fb = fired + (size_t)b * NN;
    int rowb = i0 + 32 * wr + (lane >> 4) * 4;
    int colb = j0 + 64 * wc + rl;
    #pragma unroll
    for (int fj = 0; fj < 4; ++fj) {
        int gj = colb + 16 * fj;
        float sj = s1b[gj], dj = dvb[gj];
        #pragma unroll
        for (int fi = 0; fi < 2; ++fi) {
            int gi0 = rowb + 16 * fi;
            #pragma unroll
            for (int r = 0; r < 4; ++r) {
                int gi = gi0 + r;
                if (gj > gi) {
                    float cov = acc[fi][fj][r] - s1b[gi] * sj * invT;
                    float lim = thr2 * dvb[gi] * dj;
                    if (cov * cov > lim) atomicOr(&fb[gi], 1u);
                }
            }
        }
    }
}

// ---------------- kernel C: finalize mask ----------------
__global__ __launch_bounds__(512) void finalize_mask(
    const unsigned* __restrict__ fired, float* __restrict__ out) {
    int b = blockIdx.x;
    int n = threadIdx.x;                  // 512
    unsigned f = fired[(size_t)b * NN + n];
    __shared__ int wsum[8];
    unsigned long long m = __ballot(f != 0u);
    int lane = n & 63;
    int w = n >> 6;
    if (lane == 0) wsum[w] = __popcll(m);
    __syncthreads();
    int cnt = 0;
    #pragma unroll
    for (int i = 0; i < 8; ++i) cnt += wsum[i];
    float val = (cnt == 0) ? 1.0f : ((cnt == 1) ? (f ? 1.0f : 0.0f) : 0.0f);
    out[(size_t)b * NN + n] = val;
}

extern "C" void kernel_launch(void* const* d_in, const int* in_sizes, int n_in,
                              void* d_out, int out_size, void* d_ws, size_t ws_size,
                              hipStream_t stream) {
    const float* x = (const float*)d_in[0];
    float* out = (float*)d_out;

    // ws layout
    float* s1p = (float*)d_ws;                       // B*TCH*N
    float* s2p = s1p + (size_t)BB * TCH * NN;        // B*TCH*N
    float* s1  = s2p + (size_t)BB * TCH * NN;        // B*N
    float* dv  = s1  + (size_t)BB * NN;              // B*N
    unsigned* fired = (unsigned*)(dv + (size_t)BB * NN); // B*N

    hipMemsetAsync(fired, 0, (size_t)BB * NN * sizeof(unsigned), stream);

    colsum_partial<<<dim3(BB, TCH), 512, 0, stream>>>(x, s1p, s2p);
    colsum_reduce<<<BB, 512, 0, stream>>>(s1p, s2p, s1, dv);
    corr_mfma<<<dim3(640), 512, 0, stream>>>(x, s1, dv, fired);
    finalize_mask<<<BB, 512, 0, stream>>>(fired, out);
}

// Round 5
// 130.434 us; speedup vs baseline: 1.0165x; 1.0165x over previous
//
#include <hip/hip_runtime.h>
#include <hip/hip_bf16.h>

#define BB 64
#define TT 1024
#define NN 512
#define TCH 8
#define KT 32
#define LISTCAP (1u << 20)

static constexpr float THR = 0.15f;

typedef __attribute__((ext_vector_type(8))) short bf16x8;
typedef __attribute__((ext_vector_type(4))) float f32x4;

// ---------------- kernel A: partial column sums (s1, s2, sl2) ----------------
// l = v - rtz_bf16(v) (exact residual of the truncation used in corr_mfma staging)
__global__ __launch_bounds__(512) void colsum_partial(
    const float* __restrict__ x, float* __restrict__ s1p, float* __restrict__ s2p,
    float* __restrict__ slp) {
    int b = blockIdx.x;
    int c = blockIdx.y;
    int n = threadIdx.x;                 // 0..511, coalesced over n
    const float* xb = x + (size_t)b * TT * NN;
    float s1 = 0.f, s2 = 0.f, sl = 0.f;
    int t0 = c * (TT / TCH);
    #pragma unroll 4
    for (int t = t0; t < t0 + TT / TCH; ++t) {
        float v = xb[(size_t)t * NN + n];
        s1 += v;
        s2 += v * v;
        float h = __uint_as_float(__float_as_uint(v) & 0xFFFF0000u);  // RTZ bf16
        float l = v - h;                                              // exact
        sl += l * l;
    }
    s1p[((size_t)b * TCH + c) * NN + n] = s1;
    s2p[((size_t)b * TCH + c) * NN + n] = s2;
    slp[((size_t)b * TCH + c) * NN + n] = sl;
}

// ---------------- kernel A2: reduce partials -> s1, dv, nv, nl ----------------
__global__ __launch_bounds__(512) void colsum_reduce(
    const float* __restrict__ s1p, const float* __restrict__ s2p,
    const float* __restrict__ slp, float* __restrict__ s1,
    float* __restrict__ dv, float* __restrict__ nv, float* __restrict__ nl) {
    int b = blockIdx.x;
    int n = threadIdx.x;
    float a = 0.f, q = 0.f, ql = 0.f;
    #pragma unroll
    for (int c = 0; c < TCH; ++c) {
        a  += s1p[((size_t)b * TCH + c) * NN + n];
        q  += s2p[((size_t)b * TCH + c) * NN + n];
        ql += slp[((size_t)b * TCH + c) * NN + n];
    }
    s1[(size_t)b * NN + n] = a;
    dv[(size_t)b * NN + n] = q - a * a * (1.0f / TT);   // = cov_ii (unnormalized)
    nv[(size_t)b * NN + n] = sqrtf(q);                  // ||x_col||
    nl[(size_t)b * NN + n] = sqrtf(ql);                 // ||l_col||
}

// ---------------- kernel B: bf16-hh MFMA SYRK with certainty bound ----------------
// 128x128 tile per block; 10 upper tiles x 64 batches = 640 blocks; 512 thr = 8 waves,
// wave-tile 32x64. hh-ONLY pass (was 3 passes): cov_hh error bounded per-pair by
// Cauchy-Schwarz  B_ij = nl_i*nv_j + nl_j*nv_i + 3*nl_i*nl_j (+1e-3*nv_i*nv_j margin
// for f32 MFMA accumulation slop). Certain-fired / certain-clean decided here;
// uncertain pairs appended to a global list and re-decided exactly by cleanup_pairs.
// LDS: 2 x 16 KiB double buffer (Ah @0, Bh @8K per buf), col-major [col][k] bf16,
// 64B col stride, slot-swizzle byte(col,k)=col*64+(((k>>3)^((col>>1)&3))&3)*16+(k&7)*2
// (measured conflict-free). Single-barrier 2-phase loop: LOADS(t+1) || COMPUTE(cur)
// -> WRITE(cur^1) -> one __syncthreads; load latency hides under COMPUTE inside the
// iteration, so the barrier's vmcnt drain costs nothing.
__global__ __launch_bounds__(512, 4) void corr_mfma(
    const float* __restrict__ x, const float* __restrict__ s1,
    const float* __restrict__ dv, const float* __restrict__ nv,
    const float* __restrict__ nl, unsigned* __restrict__ fired,
    unsigned* __restrict__ cnt, unsigned* __restrict__ list) {
    __shared__ uint4 ldsbuf[2048];          // 32 KiB = 2 x 16 KiB
    char* base = (char*)ldsbuf;

    int id = blockIdx.x;
    // XCD-chunked swizzle (640 = 8 * 80): all 10 tiles of a batch land on one XCD
    int swz = ((id & 7) * 80) + (id >> 3);
    int b = swz / 10;
    int u = swz % 10;
    int ti = 0, rem = u;
    while (rem >= (4 - ti)) { rem -= (4 - ti); ++ti; }
    int tj = ti + rem;
    int i0 = ti * 128, j0 = tj * 128;
    bool diag = (ti == tj);

    const unsigned* xb = (const unsigned*)(x + (size_t)b * TT * NN);
    int tid = threadIdx.x;
    int wave = tid >> 6;
    int lane = tid & 63;
    int rl = lane & 15, kg = lane >> 4;

    // ---- staging role: col-pair cp (0-63 A-panel, 64-127 B-panel), k-octet kq ----
    int cp = tid & 127;
    int kq = tid >> 7;                      // 0..3 -> k in [8*kq, 8*kq+8)
    int spanel = cp >> 6;                   // 0 = A (i-panel), 1 = B (j-panel)
    int pl = cp & 63;                       // pair index within panel -> cols 2pl, 2pl+1
    int gcol = (spanel ? j0 : i0) + 2 * pl;
    unsigned sregion = spanel ? 8192u : 0u;
    unsigned sg = (unsigned)(pl & 3);       // ((col>>1)&3) for both cols of the pair
    bool do_stage = !(diag && spanel);      // diagonal tiles: stage A only

    auto LOADS = [&](uint2* v, int step) {
        const unsigned* src = xb + (size_t)(step * KT + 8 * kq) * NN + gcol;
        #pragma unroll
        for (int j = 0; j < 8; ++j)
            v[j] = *(const uint2*)(src + (size_t)j * NN);
    };
    // h = RTZ bf16 (top 16 bits) -- consistent with colsum's l = v - trunc(v)
    auto WRITE = [&](char* bufb, const uint2* v) {
        char* shh = bufb + sregion;
        #pragma unroll
        for (int w = 0; w < 2; ++w) {
            int p = (((cp >> 2) & 1) ^ w);      // bank-quad parity order
            unsigned coll = (unsigned)(2 * pl + p);
            unsigned h32[4];
            #pragma unroll
            for (int q = 0; q < 4; ++q) {
                unsigned u0 = p ? v[2 * q].y     : v[2 * q].x;
                unsigned u1 = p ? v[2 * q + 1].y : v[2 * q + 1].x;
                h32[q] = (u0 >> 16) | (u1 & 0xFFFF0000u);
            }
            unsigned off = coll * 64u + ((((unsigned)kq ^ sg) & 3u) << 4);
            *(uint4*)(shh + off) = make_uint4(h32[0], h32[1], h32[2], h32[3]);
        }
    };

    // ---- compute role: wave (wr, wc) owns rows [32*wr,+32) x cols [64*wc,+64) ----
    int wr = wave >> 1, wc = wave & 1;
    bool skip_mm = diag && (wc == 0) && (wr >= 2);   // fully below diagonal

    f32x4 acc[2][4];
    #pragma unroll
    for (int i = 0; i < 2; ++i)
        #pragma unroll
        for (int j = 0; j < 4; ++j)
            acc[i][j] = (f32x4)0.0f;

    unsigned aoff[2], boff[4];
    #pragma unroll
    for (int f = 0; f < 2; ++f) {
        unsigned ca = (unsigned)(32 * wr + 16 * f + rl);
        aoff[f] = ca * 64u + ((((unsigned)kg ^ ((ca >> 1) & 3u)) & 3u) << 4);
    }
    #pragma unroll
    for (int f = 0; f < 4; ++f) {
        unsigned cb = (unsigned)(64 * wc + 16 * f + rl);
        boff[f] = cb * 64u + ((((unsigned)kg ^ ((cb >> 1) & 3u)) & 3u) << 4);
    }
    unsigned broff = diag ? 0u : 8192u;

    uint2 v[8];
    if (do_stage) { LOADS(v, 0); WRITE(base, v); }
    __syncthreads();

    int cur = 0;
    for (int it = 0; it < 32; ++it) {
        bool more = (it + 1 < 32);
        if (do_stage && more) LOADS(v, it + 1);     // in flight under COMPUTE

        const char* cbuf = base + (cur << 14);
        if (!skip_mm) {
            bf16x8 Ah[2];
            #pragma unroll
            for (int f = 0; f < 2; ++f)
                Ah[f] = *(const bf16x8*)(cbuf + aoff[f]);
            #pragma unroll
            for (int fj = 0; fj < 4; ++fj) {
                bf16x8 Bh = *(const bf16x8*)(cbuf + broff + boff[fj]);
                #pragma unroll
                for (int fi = 0; fi < 2; ++fi)
                    acc[fi][fj] = __builtin_amdgcn_mfma_f32_16x16x32_bf16(
                        Ah[fi], Bh, acc[fi][fj], 0, 0, 0);
            }
        }

        if (do_stage && more) WRITE(base + ((cur ^ 1) << 14), v);
        __syncthreads();
        cur ^= 1;
    }

    // ---- epilogue: c = acc - s1_i*s1_j/T;  lim = thr^2*d_i*d_j ----
    // certain fired: (|c|-B)^2 > lim (with |c|>B); certain clean: (|c|+B)^2 <= lim;
    // else append to list for exact recompute.
    const float thr2 = THR * THR;
    const float invT = 1.0f / TT;
    const float* s1b = s1 + (size_t)b * NN;
    const float* dvb = dv + (size_t)b * NN;
    const float* nvb = nv + (size_t)b * NN;
    const float* nlb = nl + (size_t)b * NN;
    unsigned* fb = fired + (size_t)b * NN;
    int rowb = i0 + 32 * wr + (lane >> 4) * 4;
    int colb = j0 + 64 * wc + rl;
    #pragma unroll
    for (int fj = 0; fj < 4; ++fj) {
        int gj = colb + 16 * fj;
        float sj = s1b[gj], djv = dvb[gj];
        float nvj = nvb[gj], nlj = nlb[gj];
        #pragma unroll
        for (int fi = 0; fi < 2; ++fi) {
            int gi0 = rowb + 16 * fi;
            #pragma unroll
            for (int r = 0; r < 4; ++r) {
                int gi = gi0 + r;
                if (gj > gi) {
                    float c = acc[fi][fj][r] - s1b[gi] * sj * invT;
                    float lim = thr2 * dvb[gi] * djv;
                    float nvi = nvb[gi], nli = nlb[gi];
                    float B = nli * nvj + nlj * nvi + 3.0f * nli * nlj
                              + 1e-3f * nvi * nvj;
                    float a = fabsf(c);
                    float lo = a - B;
                    if (lo > 0.0f && lo * lo > lim) {
                        atomicOr(&fb[gi], 1u);
                    } else if ((a + B) * (a + B) > lim) {
                        unsigned idx = atomicAdd(cnt, 1u);
                        if (idx < LISTCAP)
                            list[idx] = ((unsigned)b << 18) | ((unsigned)gi << 9)
                                        | (unsigned)gj;
                    }
                }
            }
        }
    }
}

// ---------------- kernel B2: exact recompute of borderline pairs ----------------
__global__ __launch_bounds__(256) void cleanup_pairs(
    const float* __restrict__ x, const float* __restrict__ s1,
    const float* __restrict__ dv, const unsigned* __restrict__ cnt,
    const unsigned* __restrict__ list, unsigned* __restrict__ fired) {
    unsigned n = *cnt;
    if (n > LISTCAP) n = LISTCAP;
    int lane = threadIdx.x & 63;
    int gw = (blockIdx.x * 256 + threadIdx.x) >> 6;
    int nw = (gridDim.x * 256) >> 6;
    for (unsigned p = gw; p < n; p += nw) {
        unsigned e = list[p];
        int b = e >> 18, i = (e >> 9) & 511, j = e & 511;
        const float* xb = x + (size_t)b * TT * NN;
        double s = 0.0;
        for (int t = lane; t < TT; t += 64)
            s += (double)xb[(size_t)t * NN + i] * (double)xb[(size_t)t * NN + j];
        #pragma unroll
        for (int o = 32; o > 0; o >>= 1)
            s += __shfl_xor(s, o, 64);
        if (lane == 0) {
            double cov = s - (double)s1[(size_t)b * NN + i]
                             * (double)s1[(size_t)b * NN + j] / (double)TT;
            double lim = (double)THR * (double)THR
                         * (double)dv[(size_t)b * NN + i]
                         * (double)dv[(size_t)b * NN + j];
            if (cov * cov > lim) atomicOr(&fired[(size_t)b * NN + i], 1u);
        }
    }
}

// ---------------- kernel C: finalize mask ----------------
__global__ __launch_bounds__(512) void finalize_mask(
    const unsigned* __restrict__ fired, float* __restrict__ out) {
    int b = blockIdx.x;
    int n = threadIdx.x;                  // 512
    unsigned f = fired[(size_t)b * NN + n];
    __shared__ int wsum[8];
    unsigned long long m = __ballot(f != 0u);
    int lane = n & 63;
    int w = n >> 6;
    if (lane == 0) wsum[w] = __popcll(m);
    __syncthreads();
    int cnt = 0;
    #pragma unroll
    for (int i = 0; i < 8; ++i) cnt += wsum[i];
    float val = (cnt == 0) ? 1.0f : ((cnt == 1) ? (f ? 1.0f : 0.0f) : 0.0f);
    out[(size_t)b * NN + n] = val;
}

extern "C" void kernel_launch(void* const* d_in, const int* in_sizes, int n_in,
                              void* d_out, int out_size, void* d_ws, size_t ws_size,
                              hipStream_t stream) {
    const float* x = (const float*)d_in[0];
    float* out = (float*)d_out;

    // ws layout
    float* s1p = (float*)d_ws;                       // B*TCH*N
    float* s2p = s1p + (size_t)BB * TCH * NN;        // B*TCH*N
    float* slp = s2p + (size_t)BB * TCH * NN;        // B*TCH*N
    float* s1  = slp + (size_t)BB * TCH * NN;        // B*N
    float* dv  = s1  + (size_t)BB * NN;              // B*N
    float* nv  = dv  + (size_t)BB * NN;              // B*N
    float* nl  = nv  + (size_t)BB * NN;              // B*N
    unsigned* fired = (unsigned*)(nl + (size_t)BB * NN); // B*N
    unsigned* cnt   = fired + (size_t)BB * NN;           // 16 (padded)
    unsigned* list  = cnt + 16;                          // LISTCAP

    // zero fired + cnt in one contiguous memset
    hipMemsetAsync(fired, 0, ((size_t)BB * NN + 16) * sizeof(unsigned), stream);

    colsum_partial<<<dim3(BB, TCH), 512, 0, stream>>>(x, s1p, s2p, slp);
    colsum_reduce<<<BB, 512, 0, stream>>>(s1p, s2p, slp, s1, dv, nv, nl);
    corr_mfma<<<dim3(640), 512, 0, stream>>>(x, s1, dv, nv, nl, fired, cnt, list);
    cleanup_pairs<<<128, 256, 0, stream>>>(x, s1, dv, cnt, list, fired);
    finalize_mask<<<BB, 512, 0, stream>>>(fired, out);
}